// Round 8
// baseline (87.598 us; speedup 1.0000x reference)
//
#include <hip/hip_runtime.h>
#include <hip/hip_bf16.h>

#pragma clang fp contract(off)

#define NN   230400   // H*W*A
#define NK   128      // gt boxes
#define HW_  25600    // H*W
#define NA   9
#define NBLK 900      // NN/256
#define BINS 8192
#define BCAP 64

// ---- scalar slots in ws ----
enum { S_FG_ACTIVE=0, S_FG_TH, S_NFG_FINAL, S_BG_ACTIVE, S_BG_TH, S_NUM_EX };

__device__ __forceinline__ unsigned encf(float f) {
    unsigned u = __float_as_uint(f);
    return (u & 0x80000000u) ? ~u : (u | 0x80000000u);
}
__device__ __forceinline__ float decf(unsigned e) {
    unsigned u = (e & 0x80000000u) ? (e & 0x7FFFFFFFu) : ~e;
    return __uint_as_float(u);
}
// The ONE IoU expression (identical rounding at every use site; contract off).
__device__ __forceinline__ void iou_parts(float4 a, float ba, float4 g, float ga,
                                          float& I, float& D) {
    float iw = fmaxf(fminf(a.z, g.z) - fmaxf(a.x, g.x) + 1.0f, 0.0f);
    float ih = fmaxf(fminf(a.w, g.w) - fmaxf(a.y, g.y) + 1.0f, 0.0f);
    I = iw * ih;
    D = ba + ga - I;          // (ba+ga)-I, same assoc everywhere
}
__device__ __forceinline__ unsigned vbin(float nz) {
    unsigned b = (unsigned)(nz * 8192.0f);
    return b > 8191u ? 8191u : b;
}
// Guarded rational compare: returns true iff round(nI/nD) > round(bI/bD).
// Clear band (>6 ulp rational gap) decides without divide; ambiguity -> exact.
__device__ __forceinline__ bool rgt(float nI, float nD, float bI, float bD) {
    float c1 = nI * bD, c2 = bI * nD;
    if (!(c1 > c2 * (1.0f - 1e-6f))) return false;
    if (c1 > c2 * (1.0f + 1e-6f)) return true;
    float vn = nI / nD, vb = bI / bD;      // exact IEEE resolve
    return vn > vb;
}

__global__ __launch_bounds__(256) void k_init(unsigned* __restrict__ p, int n) {
    int i = blockIdx.x * blockDim.x + threadIdx.x;
    for (; i < n; i += gridDim.x * blockDim.x) p[i] = 0u;
}

// Fused row+col pass, 128 anchors x 128 gts per block; each IoU computed ONCE.
// Thread (rg,cg) owns an 8x8 subtile; rational partials merged in LDS.
__global__ __launch_bounds__(256) void k_rowcol(
    const float4* __restrict__ anchors, const float4* __restrict__ gt,
    const float* __restrict__ iminfo, float* __restrict__ maxov,
    unsigned char* __restrict__ argm, unsigned* __restrict__ gtm) {
    __shared__ float4 sg[NK];
    __shared__ float  sga[NK];
    __shared__ float4 sa[128];
    __shared__ float  sba[128];              // real ba, or -1 if outside
    __shared__ float  pI[16][129], pD[16][129];    // row partials (padded)
    __shared__ unsigned char pidx[16][129];
    __shared__ float  cpI[16][129], cpD[16][129];  // col partials (padded)
    int t = threadIdx.x;
    if (t < NK) {
        float4 g = gt[t];
        sg[t] = g;
        sga[t] = (g.z - g.x + 1.0f) * (g.w - g.y + 1.0f);
    }
    int base = blockIdx.x * 128;
    if (t < 128) {
        float4 a = anchors[base + t];
        sa[t] = a;
        float imh = iminfo[0], imw = iminfo[1];
        bool ins = (a.x >= 0.0f) && (a.y >= 0.0f) && (a.z < imw) && (a.w < imh);
        float ba = (a.z - a.x + 1.0f) * (a.w - a.y + 1.0f);
        sba[t] = ins ? ba : -1.0f;
    }
    __syncthreads();
    int rg = t >> 4, cg = t & 15;            // 16x16 thread grid of 8x8 subtiles
    // load this thread's 8 gts to registers
    float4 G[8]; float GA[8];
    #pragma unroll
    for (int c = 0; c < 8; ++c) { G[c] = sg[cg * 8 + c]; GA[c] = sga[cg * 8 + c]; }
    float cIv[8], cDv[8];
    #pragma unroll
    for (int c = 0; c < 8; ++c) { cIv[c] = 0.0f; cDv[c] = 1.0f; }
    #pragma unroll
    for (int r = 0; r < 8; ++r) {
        int ai = rg * 8 + r;
        float4 a = sa[ai];
        float ba = sba[ai];
        bool act = ba >= 0.0f;
        float rI = 0.0f, rD = 1.0f;
        int ridx = cg * 8;                   // value-0 at first k of range
        #pragma unroll
        for (int c = 0; c < 8; ++c) {
            float I, Dd; iou_parts(a, ba, G[c], GA[c], I, Dd);
            if (act && I > 0.0f) {           // zeros never beat best >= 0
                if (rgt(I, Dd, rI, rD)) { rI = I; rD = Dd; ridx = cg * 8 + c; }
                if (rgt(I, Dd, cIv[c], cDv[c])) { cIv[c] = I; cDv[c] = Dd; }
            }
        }
        pI[cg][ai] = rI; pD[cg][ai] = rD; pidx[cg][ai] = (unsigned char)ridx;
    }
    #pragma unroll
    for (int c = 0; c < 8; ++c) { cpI[rg][cg * 8 + c] = cIv[c]; cpD[rg][cg * 8 + c] = cDv[c]; }
    __syncthreads();
    if (t < 128) {
        // row reduce: merge 16 k-range partials ascending (first-max preserved)
        int i = t;
        float bI = pI[0][i], bD = pD[0][i];
        int bidx = pidx[0][i];
        #pragma unroll
        for (int g2 = 1; g2 < 16; ++g2) {
            float nI = pI[g2][i], nD = pD[g2][i];
            if (rgt(nI, nD, bI, bD)) { bI = nI; bD = nD; bidx = pidx[g2][i]; }
        }
        float v = bI / bD;                   // exact rounded row max
        bool outs = sba[i] < 0.0f;
        maxov[base + i] = outs ? -1.0f : v;
        argm[base + i]  = (unsigned char)(outs ? 0 : bidx);
    } else {
        // col reduce (concurrent): merge 16 anchor-group partials
        int j = t - 128;
        float bI = cpI[0][j], bD = cpD[0][j];
        #pragma unroll
        for (int r2 = 1; r2 < 16; ++r2) {
            float nI = cpI[r2][j], nD = cpD[r2][j];
            if (rgt(nI, nD, bI, bD)) { bI = nI; bD = nD; }
        }
        float w = bI / bD;                   // exact rounded block col max
        unsigned e = encf(w);
        if (e > gtm[j]) atomicMax(&gtm[j], e);   // racy prefilter; atomic wins
    }
}

// Labels: in-block gt sort by gt_max (ascending, ties by index), thresholds from
// maxov, gt-best resolved inline for deferred anchors, value-binned hist+bucket.
__global__ __launch_bounds__(256) void k_labels(
    const float4* __restrict__ anchors, const float4* __restrict__ gt,
    const unsigned* __restrict__ gtm,
    const float* __restrict__ maxov, const float* __restrict__ noise,
    float* __restrict__ labels,
    unsigned* __restrict__ hfv, unsigned* __restrict__ hbv,
    float* __restrict__ bfv, float* __restrict__ bbv) {
    __shared__ float4 sg[NK];
    __shared__ float  sga[NK];
    __shared__ float  sgm[NK];
    __shared__ unsigned se[NK];
    int t = threadIdx.x;
    if (t < NK) se[t] = gtm[t];
    __syncthreads();
    if (t < NK) {
        unsigned e = se[t];
        int rank = 0;
        for (int j = 0; j < NK; ++j) {
            unsigned ej = se[j];
            rank += (ej < e) || (ej == e && j < t);
        }
        float4 g = gt[t];
        sg[rank]  = g;
        sga[rank] = (g.z - g.x + 1.0f) * (g.w - g.y + 1.0f);
        sgm[rank] = decf(e);
    }
    __syncthreads();
    int i = blockIdx.x * 256 + t;
    float mo = maxov[i];
    bool ins = mo >= 0.0f;
    float smin = sgm[0];
    float lab = -1.0f;
    if (ins && mo < 0.3f)  lab = 0.0f;
    if (ins && mo >= 0.7f) lab = 1.0f;
    bool defer = ins && (mo >= smin) && (mo < 0.7f);
    if (defer) {                               // rare -> divergence cost small
        float4 a = anchors[i];
        float ba = (a.z - a.x + 1.0f) * (a.w - a.y + 1.0f);
        bool gb = false;
        for (int q = 0; q < NK; ++q) {
            float gm = sgm[q];
            if (gm > mo) break;                // sorted: no later column can match
            float I, D; iou_parts(a, ba, sg[q], sga[q], I, D);
            float v = I / D;                   // bit-identical to k_rowcol rounding
            gb = gb || (v == gm);
        }
        if (gb) lab = 1.0f;
    }
    labels[i] = lab;
    float nz = noise[i];
    if (lab == 1.0f) {
        unsigned b = vbin(nz);
        unsigned s = atomicAdd(&hfv[b], 1u);
        if (s < BCAP) bfv[b * BCAP + s] = nz;
    } else if (lab == 0.0f) {
        unsigned b = vbin(nz);
        unsigned s = atomicAdd(&hbv[b], 1u);
        if (s < BCAP) bbv[b * BCAP + s] = nz;
    }
}

// Selection body: linear 8192-bin scan -> bin+rem -> exact rank among <=64 values.
__device__ __forceinline__ void sel_body(
    const unsigned* __restrict__ hist, const float* __restrict__ bucket,
    unsigned* __restrict__ sc, int isBg,
    int* csum, int* suf, int* sscal, float* sv) {
    int t = threadIdx.x;
    const unsigned* hp = hist + t * 32;
    int s = 0;
    for (int b = 0; b < 32; ++b) s += (int)hp[b];
    csum[t] = s;
    if (t == 0) { sscal[0] = 0; sscal[1] = 1; }
    __syncthreads();
    if (t == 0) {
        int run = 0;
        for (int c = 255; c >= 0; --c) { suf[c] = run; run += csum[c]; }
        sscal[2] = run;
    }
    __syncthreads();
    int total = sscal[2];
    int k, active;
    if (isBg) {
        int nfg = (int)sc[S_NFG_FINAL];
        int nb = 256 - nfg;
        active = total > nb;
        k = nb < 1 ? 1 : nb;
    } else {
        active = total > 128;
        k = 128;
    }
    if (!active) {
        if (t == 0) {
            if (isBg) { sc[S_BG_ACTIVE] = 0u; sc[S_NUM_EX] = sc[S_NFG_FINAL] + (unsigned)total; }
            else      { sc[S_FG_ACTIVE] = 0u; sc[S_NFG_FINAL] = (unsigned)total; }
        }
    } else {
        int above = suf[t];
        if (above < k && k <= above + csum[t]) {
            int c = above;
            for (int b = 31; b >= 0; --b) {
                int hh = (int)hp[b];
                c += hh;
                if (c >= k) { sscal[0] = t * 32 + b; sscal[1] = k - (c - hh); break; }
            }
        }
    }
    __syncthreads();
    if (active) {                                  // block-uniform condition
        int bstar = sscal[0], rem = sscal[1];
        int cnt = (int)hist[bstar];
        if (cnt > BCAP) cnt = BCAP;
        if (t < BCAP) sv[t] = (t < cnt) ? bucket[bstar * BCAP + t] : -INFINITY;
        __syncthreads();
        if (t < cnt) {
            float v = sv[t];
            int a = 0, b2 = 0;
            for (int q = 0; q < cnt; ++q) { float u = sv[q]; a += (u > v); b2 += (u == v); }
            if (a < rem && rem <= a + b2) {        // v is the k-th largest (tie-exact)
                unsigned nk = (unsigned)(k - rem + a + b2);   // count(score >= th)
                if (isBg) { sc[S_BG_TH] = __float_as_uint(v); sc[S_BG_ACTIVE] = 1u;
                            sc[S_NUM_EX] = sc[S_NFG_FINAL] + nk; }
                else      { sc[S_FG_TH] = __float_as_uint(v); sc[S_FG_ACTIVE] = 1u;
                            sc[S_NFG_FINAL] = nk; }
            }
        }
    }
    __syncthreads();                               // publish sc before next pass
}

__global__ __launch_bounds__(256) void k_select(
    const unsigned* __restrict__ hfv, const float* __restrict__ bfv,
    const unsigned* __restrict__ hbv, const float* __restrict__ bbv,
    unsigned* __restrict__ sc) {
    __shared__ int csum[256];
    __shared__ int suf[256];
    __shared__ int sscal[3];
    __shared__ float sv[BCAP];
    sel_body(hfv, bfv, sc, 0, csum, suf, sscal, sv);
    sel_body(hbv, bbv, sc, 1, csum, suf, sscal, sv);
}

// Final: apply disables, permuted label write, targets, weights
__global__ __launch_bounds__(256) void k_final(
    const float4* __restrict__ anchors, const float4* __restrict__ gt,
    const float* __restrict__ noise, const float* __restrict__ labels,
    const unsigned char* __restrict__ argm, const float* __restrict__ maxov,
    const unsigned* __restrict__ sc,
    float* __restrict__ out0, float4* __restrict__ out1,
    float4* __restrict__ out2, float4* __restrict__ out3) {
    int i = blockIdx.x * 256 + threadIdx.x;
    unsigned fga = sc[S_FG_ACTIVE], bga = sc[S_BG_ACTIVE];
    float thf = __uint_as_float(sc[S_FG_TH]);
    float thb = __uint_as_float(sc[S_BG_TH]);

    // out0: dest-indexed permuted labels. dest i = a*HW + cell; src = cell*NA + a
    {
        int a0 = i / HW_, cell0 = i % HW_;
        int src = cell0 * NA + a0;
        float lab0 = labels[src];
        float nz0 = noise[src];
        if (fga && lab0 == 1.0f && nz0 < thf) lab0 = -1.0f;
        if (bga && lab0 == 0.0f && nz0 < thb) lab0 = -1.0f;
        out0[i] = lab0;
    }

    float lab = labels[i];
    float nz = noise[i];
    if (fga && lab == 1.0f && nz < thf) lab = -1.0f;
    if (bga && lab == 0.0f && nz < thb) lab = -1.0f;

    float4 an = anchors[i];
    float4 g = gt[argm[i]];
    float ew = an.z - an.x + 1.0f, eh = an.w - an.y + 1.0f;
    float ecx = an.x + 0.5f * ew,  ecy = an.y + 0.5f * eh;
    float gw = g.z - g.x + 1.0f,   gh = g.w - g.y + 1.0f;
    float gcx = g.x + 0.5f * gw,   gcy = g.y + 0.5f * gh;
    float t0 = (gcx - ecx) / ew;
    float t1 = (gcy - ecy) / eh;
    float t2 = logf(gw / ew);
    float t3 = logf(gh / eh);
    if (maxov[i] < 0.0f) { t0 = 0.0f; t1 = 0.0f; t2 = 0.0f; t3 = 0.0f; }  // outside
    out1[i] = make_float4(t0, t1, t2, t3);

    float biw = (lab == 1.0f) ? 1.0f : 0.0f;
    out2[i] = make_float4(biw, biw, biw, biw);

    float inv = 1.0f / (float)sc[S_NUM_EX];
    float bow = (lab >= 0.0f) ? inv : 0.0f;
    out3[i] = make_float4(bow, bow, bow, bow);
}

extern "C" void kernel_launch(void* const* d_in, const int* in_sizes, int n_in,
                              void* d_out, int out_size, void* d_ws, size_t ws_size,
                              hipStream_t stream) {
    const float4* anchors = (const float4*)d_in[0];
    const float4* gt      = (const float4*)d_in[1];
    const float*  iminfo  = (const float*)d_in[2];
    const float*  noise   = (const float*)d_in[3];

    float*  out0 = (float*)d_out;                  // NN
    float4* out1 = (float4*)(out0 + NN);           // NN x 4
    float4* out2 = (float4*)(out0 + NN + 4 * NN);  // NN x 4
    float4* out3 = (float4*)(out0 + NN + 8 * NN);  // NN x 4

    // value buckets live in the (not-yet-written) out1/out2 region of d_out:
    // written by k_labels, read by k_select, then k_final overwrites out1/out2.
    float* bfv = out0 + NN;                        // BINS*BCAP floats = 2MB
    float* bbv = bfv + BINS * BCAP;                // 2MB more

    char* ws = (char*)d_ws;
    unsigned* sc   = (unsigned*)ws;                         // 128 u32
    unsigned* gtm  = (unsigned*)(ws + 512);                 // 128 u32
    unsigned* hfv  = (unsigned*)(ws + 4096);                // 8192 u32
    unsigned* hbv  = hfv + BINS;                            // 8192 u32 -> ends 69632
    float* labels  = (float*)(ws + 69632);                  // NN f32
    float* maxov   = labels + NN;                           // NN f32
    unsigned char* argm = (unsigned char*)(maxov + NN);     // NN u8

    k_init<<<68, 256, 0, stream>>>((unsigned*)ws, 17408);   // sc+gtm+hists
    k_rowcol<<<1800, 256, 0, stream>>>(anchors, gt, iminfo, maxov, argm, gtm);
    k_labels<<<NBLK, 256, 0, stream>>>(anchors, gt, gtm, maxov, noise,
                                       labels, hfv, hbv, bfv, bbv);
    k_select<<<1, 256, 0, stream>>>(hfv, bfv, hbv, bbv, sc);
    k_final<<<NBLK, 256, 0, stream>>>(anchors, gt, noise, labels, argm, maxov, sc,
                                      out0, out1, out2, out3);
}